// Round 1
// baseline (358.331 us; speedup 1.0000x reference)
//
#include <hip/hip_runtime.h>

// GaussianKernel: out[b,n,m] = exp(inv2s * (||Q[b,n]||^2 + ||KV[b,:,m]||^2 - 2*Q[b,n]·KV[b,:,m]))
// B=16, N=2048, M=2048, D=128, fp32 in/out.
//
// R2: single fused kernel (no prep kernels, no workspace round-trip).
//  - 128x128 tile / block, 4 waves (2x2 of 64x64), fp16 MFMA 16x16x32.
//  - K split into two 64-wide halves, single-buffered: LDS = 33.3 KB -> 3-4 blocks/CU
//    (was 67.5 KB -> 2 blocks/CU).
//  - Reg-staged f32 loads + in-register RTN fp16 convert + XOR-granule-swizzled
//    ds_write_b128; Qsq/Ksq computed on the fly (shfl_xor pair reduce -> 1KB LDS).
//  - Epilogue: direct global_store_dword, each wave instr = 4 fully-covered aligned
//    64B lines (no write amplification), no C-stage LDS round trip.

#define B_  16
#define N_  2048
#define M_  2048
#define D_  128

typedef _Float16 half8 __attribute__((ext_vector_type(8)));
typedef float    f32x4 __attribute__((ext_vector_type(4)));

__global__ __launch_bounds__(256, 3) void gauss_fused(
    const float* __restrict__ Q, const float* __restrict__ KV,
    const float* __restrict__ ls, float* __restrict__ out) {

    // A-half [128 rows][64 k] fp16 (16KB) + B-half [128 m][64 k] fp16 (16KB)
    // + row norms (1KB). 33.3 KB total.
    __shared__ __align__(16) _Float16 Ash[128 * 64];
    __shared__ __align__(16) _Float16 Bsh[128 * 64];
    __shared__ float Qs[128];
    __shared__ float Ks[128];

    const int b  = blockIdx.y;
    int bx = blockIdx.x;
    bx = ((bx & 7) << 5) | (bx >> 3);      // XCD-contiguous chunks (256 % 8 == 0, bijective)
    const int n0 = (bx >> 4) << 7;
    const int m0 = (bx & 15) << 7;

    const int tid  = threadIdx.x;
    const int wave = tid >> 6;
    const int lane = tid & 63;

    // Staging ownership: 2 threads per row; thread covers 32 consecutive k.
    const int r     = tid >> 1;            // row (A: n-row, B: m-row) 0..127
    const int kc    = (tid & 1) << 5;      // k-chunk within half: 0 or 32
    const int gbase = (tid & 1) << 2;      // granule base: 0 or 4 (granule = 8 halves)
    const int sw    = r & 7;               // write-side XOR swizzle

    const float* Ag = Q  + ((size_t)b * N_ + n0 + r) * D_ + kc;
    const float* Bg = KV + (size_t)b * D_ * M_ + (size_t)kc * M_ + m0 + r;

    // MFMA fragment geometry (identical to verified R1 kernel).
    const int wr  = (wave >> 1) << 6;
    const int wc  = (wave & 1) << 6;
    const int lm  = lane & 15;
    const int kq  = lane >> 4;
    const int fsw = lm & 7;                // read-side XOR swizzle (row&7 == lm&7)

    float sqA = 0.f, sqB = 0.f;
    f32x4 acc[4][4] = {};

    #pragma unroll
    for (int h = 0; h < 2; ++h) {
        // ---- global loads (f32) into registers ----
        f32x4 av[8];                       // A: 32 consecutive k of own row
        #pragma unroll
        for (int j = 0; j < 8; ++j)
            av[j] = *reinterpret_cast<const f32x4*>(Ag + h * 64 + j * 4);
        float bv[32];                      // B: 32 k of own m-column (stride-M, lane-coalesced)
        #pragma unroll
        for (int j = 0; j < 32; ++j)
            bv[j] = Bg[(size_t)(h * 64 + j) * M_];

        if (h) __syncthreads();            // previous half's frag reads complete

        // ---- convert (RTN) + swizzled ds_write_b128, accumulate sum-of-squares ----
        #pragma unroll
        for (int g = 0; g < 4; ++g) {
            union { _Float16 hh[8]; half8 v; } pa;
            #pragma unroll
            for (int p = 0; p < 2; ++p) {
                const f32x4 v = av[g * 2 + p];
                sqA = fmaf(v.x, v.x, sqA);
                sqA = fmaf(v.y, v.y, sqA);
                sqA = fmaf(v.z, v.z, sqA);
                sqA = fmaf(v.w, v.w, sqA);
                pa.hh[p * 4 + 0] = (_Float16)v.x;
                pa.hh[p * 4 + 1] = (_Float16)v.y;
                pa.hh[p * 4 + 2] = (_Float16)v.z;
                pa.hh[p * 4 + 3] = (_Float16)v.w;
            }
            *reinterpret_cast<half8*>(&Ash[r * 64 + (((gbase + g) ^ sw) << 3)]) = pa.v;

            union { _Float16 hh[8]; half8 v; } pb;
            #pragma unroll
            for (int e = 0; e < 8; ++e) {
                const float x = bv[g * 8 + e];
                sqB = fmaf(x, x, sqB);
                pb.hh[e] = (_Float16)x;
            }
            *reinterpret_cast<half8*>(&Bsh[r * 64 + (((gbase + g) ^ sw) << 3)]) = pb.v;
        }

        if (h) {                           // both k-halves accumulated: finalize row norms
            sqA += __shfl_xor(sqA, 1, 64);
            sqB += __shfl_xor(sqB, 1, 64);
            if ((tid & 1) == 0) { Qs[r] = sqA; Ks[r] = sqB; }
        }
        __syncthreads();

        // ---- MFMA over this 64-wide K half ----
        #pragma unroll
        for (int s = 0; s < 2; ++s) {
            const int gl = (s << 2) + kq;  // logical granule 0..7 within half
            half8 af[4], bf[4];
            #pragma unroll
            for (int rr = 0; rr < 4; ++rr)
                af[rr] = *reinterpret_cast<const half8*>(
                    &Ash[(wr + rr * 16 + lm) * 64 + ((gl ^ fsw) << 3)]);
            #pragma unroll
            for (int cc = 0; cc < 4; ++cc)
                bf[cc] = *reinterpret_cast<const half8*>(
                    &Bsh[(wc + cc * 16 + lm) * 64 + ((gl ^ fsw) << 3)]);
            #pragma unroll
            for (int rr = 0; rr < 4; ++rr)
                #pragma unroll
                for (int cc = 0; cc < 4; ++cc)
                    acc[rr][cc] = __builtin_amdgcn_mfma_f32_16x16x32_f16(
                        af[rr], bf[cc], acc[rr][cc], 0, 0, 0);
        }
    }

    // ---- epilogue: exp + direct stores (4 aligned 64B lines per wave instr) ----
    const float inv2s = -0.5f * __expf(-2.0f * ls[0]);
    const float cm2   = -2.0f * inv2s;
    const int   l4    = kq << 2;

    float ksv[4];
    #pragma unroll
    for (int cc = 0; cc < 4; ++cc) ksv[cc] = inv2s * Ks[wc + cc * 16 + lm];
    float qsv[4][4];
    #pragma unroll
    for (int rr = 0; rr < 4; ++rr)
        #pragma unroll
        for (int i = 0; i < 4; ++i) qsv[rr][i] = inv2s * Qs[wr + rr * 16 + l4 + i];

    float* Cb = out + ((size_t)b * N_ + n0 + wr + l4) * M_ + m0 + wc + lm;
    #pragma unroll
    for (int rr = 0; rr < 4; ++rr) {
        #pragma unroll
        for (int i = 0; i < 4; ++i) {
            float* p = Cb + (size_t)(rr * 16 + i) * M_;
            #pragma unroll
            for (int cc = 0; cc < 4; ++cc) {
                const float t = fmaf(cm2, acc[rr][cc][i], qsv[rr][i] + ksv[cc]);
                p[cc * 16] = __expf(t);
            }
        }
    }
}

// ---------------------------------------------------------------- launch ----
extern "C" void kernel_launch(void* const* d_in, const int* in_sizes, int n_in,
                              void* d_out, int out_size, void* d_ws, size_t ws_size,
                              hipStream_t stream) {
    const float* Q  = (const float*)d_in[0];
    const float* KV = (const float*)d_in[1];
    const float* ls = (const float*)d_in[2];
    float* out = (float*)d_out;

    gauss_fused<<<dim3(256, B_), 256, 0, stream>>>(Q, KV, ls, out);
}

// Round 2
// 307.767 us; speedup vs baseline: 1.1643x; 1.1643x over previous
//
#include <hip/hip_runtime.h>

// GaussianKernel: out[b,n,m] = exp(inv2s * (||Q[b,n]||^2 + ||KV[b,:,m]||^2 - 2*Q[b,n]·KV[b,:,m]))
// B=16, N=2048, M=2048, D=128, fp32 in/out.
//
// R3: back to 3-kernel pipeline (preps verified in R0; convert once, perfect layouts).
// New gemm:
//  - K split in two 64-wide halves, single-buffered: LDS = 32 KB -> 3 blocks/CU
//    (launch_bounds(256,3); R0 was 67.5 KB -> 2 blocks/CU).
//  - Reg-fragment pipeline: read ALL h0 frags to regs, barrier, issue h1
//    global_load_lds, then run h0's 32 MFMAs while h1 is in flight.
//  - Direct-store epilogue (verified in R2): no C-stage LDS roundtrip, one less
//    barrier; each 16-lane group stores a full aligned 64B chunk.
//  - Same XOR-granule swizzle (write side r&7 on the GLOBAL address, read side
//    lm&7) -> conflict-free ds_read_b128 (2-way alias only, free).

#define B_  16
#define N_  2048
#define M_  2048
#define D_  128

typedef _Float16 half8 __attribute__((ext_vector_type(8)));
typedef float    f32x4 __attribute__((ext_vector_type(4)));

// ---------------------------------------------------------------- prep Q ----
__global__ __launch_bounds__(256) void prep_q(const float* __restrict__ Q,
                                              _Float16* __restrict__ Qh,
                                              float* __restrict__ Qsq) {
    const int row  = blockIdx.x * 4 + (threadIdx.x >> 6);
    const int lane = threadIdx.x & 63;
    const float2 v = reinterpret_cast<const float2*>(Q + (size_t)row * D_)[lane];
    float sq = v.x * v.x + v.y * v.y;
    union { _Float16 h[2]; unsigned int u; } pk;
    pk.h[0] = (_Float16)v.x;
    pk.h[1] = (_Float16)v.y;
    reinterpret_cast<unsigned int*>(Qh + (size_t)row * D_)[lane] = pk.u;
    #pragma unroll
    for (int off = 32; off > 0; off >>= 1) sq += __shfl_down(sq, off, 64);
    if (lane == 0) Qsq[row] = sq;
}

// --------------------------------------------------------------- prep KV ----
// KV[b, k, m] -> KTh[b, m, k] fp16 + Ksq[b, m]. Reads coalesced along m.
__global__ __launch_bounds__(256) void prep_kv(const float* __restrict__ KV,
                                               _Float16* __restrict__ KTh,
                                               float* __restrict__ Ksq) {
    const int b = blockIdx.y;
    const int m = blockIdx.x * 256 + threadIdx.x;
    const float* src = KV + (size_t)b * D_ * M_ + m;
    _Float16*   dst = KTh + ((size_t)b * M_ + m) * D_;
    float sq = 0.f;
    #pragma unroll 2
    for (int k0 = 0; k0 < D_; k0 += 8) {
        union { _Float16 h[8]; int4 v; } buf;
        #pragma unroll
        for (int j = 0; j < 8; ++j) {
            const float v = src[(size_t)(k0 + j) * M_];
            sq += v * v;
            buf.h[j] = (_Float16)v;
        }
        *reinterpret_cast<int4*>(dst + k0) = buf.v;
    }
    Ksq[(size_t)b * M_ + m] = sq;
}

// ------------------------------------------------------------------ GEMM ----
__global__ __launch_bounds__(256, 3) void gauss_gemm(
    const _Float16* __restrict__ Qh, const _Float16* __restrict__ KTh,
    const float* __restrict__ Qsq,  const float* __restrict__ Ksq,
    const float* __restrict__ ls,   float* __restrict__ out) {
    __shared__ __align__(16) _Float16 Ash[128 * 64];   // 16 KB (one K-half of A)
    __shared__ __align__(16) _Float16 Bsh[128 * 64];   // 16 KB (one K-half of B)

    const int b    = blockIdx.y;
    const int bx   = blockIdx.x;
    const int n0   = (bx >> 4) << 7;
    const int m0   = (bx & 15) << 7;
    const int tid  = threadIdx.x;
    const int wave = tid >> 6;
    const int lane = tid & 63;

    const _Float16* Ag = Qh  + ((size_t)b * N_ + n0) * D_;
    const _Float16* Bg = KTh + ((size_t)b * M_ + m0) * D_;

    // Staging geometry: granule = 16B (8 halves); 8 granules per 64-k row.
    // Thread's instr j covers global granule gi = j*256 + tid:
    //   row r = gi>>3, granule col gc = gi&7, swizzled on the GLOBAL address
    //   (logical granule gc^ (r&7)) so the LDS dst stays linear wave-uniform.
    int goff[4];
    #pragma unroll
    for (int j = 0; j < 4; ++j) {
        const int gi = j * 256 + tid;
        const int r  = gi >> 3;
        const int gc = gi & 7;
        goff[j] = r * D_ + ((gc ^ (r & 7)) << 3);   // in halves, half-offset added below
    }
    const int dbase = wave * 512;                    // halves; + j*2048

    auto STAGE = [&](int h) {
        #pragma unroll
        for (int j = 0; j < 4; ++j) {
            __builtin_amdgcn_global_load_lds(
                (const __attribute__((address_space(1))) unsigned int*)(Ag + h * 64 + goff[j]),
                (__attribute__((address_space(3))) unsigned int*)(&Ash[j * 2048 + dbase]), 16, 0, 0);
            __builtin_amdgcn_global_load_lds(
                (const __attribute__((address_space(1))) unsigned int*)(Bg + h * 64 + goff[j]),
                (__attribute__((address_space(3))) unsigned int*)(&Bsh[j * 2048 + dbase]), 16, 0, 0);
        }
    };

    // MFMA fragment geometry (identical to verified R0/R2 kernels).
    const int wr  = (wave >> 1) << 6;
    const int wc  = (wave & 1) << 6;
    const int lm  = lane & 15;
    const int kq  = lane >> 4;
    const int fsw = lm & 7;                // read-side XOR (frag row&7 == lm&7)

    auto READ = [&](half8 af[2][4], half8 bf[2][4]) {
        #pragma unroll
        for (int s = 0; s < 2; ++s) {
            const int pc = ((((s << 2) + kq) ^ fsw) << 3);
            #pragma unroll
            for (int rr = 0; rr < 4; ++rr)
                af[s][rr] = *reinterpret_cast<const half8*>(
                    &Ash[(wr + rr * 16 + lm) * 64 + pc]);
            #pragma unroll
            for (int cc = 0; cc < 4; ++cc)
                bf[s][cc] = *reinterpret_cast<const half8*>(
                    &Bsh[(wc + cc * 16 + lm) * 64 + pc]);
        }
    };

    f32x4 acc[4][4] = {};
    auto MFMA = [&](half8 af[2][4], half8 bf[2][4]) {
        #pragma unroll
        for (int s = 0; s < 2; ++s)
            #pragma unroll
            for (int rr = 0; rr < 4; ++rr)
                #pragma unroll
                for (int cc = 0; cc < 4; ++cc)
                    acc[rr][cc] = __builtin_amdgcn_mfma_f32_16x16x32_f16(
                        af[s][rr], bf[s][cc], acc[rr][cc], 0, 0, 0);
    };

    STAGE(0);
    __syncthreads();                       // h0 in LDS (syncthreads drains vmcnt)

    half8 a0[2][4], b0[2][4];
    READ(a0, b0);                          // all h0 frags -> regs
    __syncthreads();                       // all waves' reads done -> LDS reusable

    STAGE(1);                              // h1 in flight ...
    MFMA(a0, b0);                          // ... hidden under h0's 32 MFMAs
    __syncthreads();                       // h1 in LDS

    half8 a1[2][4], b1[2][4];
    READ(a1, b1);
    MFMA(a1, b1);

    // ---- epilogue: exp + direct stores (each 16-lane group = aligned 64B line)
    const float inv2s = -0.5f * __expf(-2.0f * ls[0]);
    const float cm2   = -2.0f * inv2s;
    const int   l4    = kq << 2;
    const float* qsq = Qsq + (size_t)b * N_ + n0;
    const float* ksq = Ksq + (size_t)b * M_ + m0;

    float ksv[4];
    #pragma unroll
    for (int cc = 0; cc < 4; ++cc) ksv[cc] = inv2s * ksq[wc + cc * 16 + lm];
    float qsv[4][4];
    #pragma unroll
    for (int rr = 0; rr < 4; ++rr)
        #pragma unroll
        for (int i = 0; i < 4; ++i) qsv[rr][i] = inv2s * qsq[wr + rr * 16 + l4 + i];

    float* Cb = out + ((size_t)b * N_ + n0 + wr + l4) * M_ + m0 + wc + lm;
    #pragma unroll
    for (int rr = 0; rr < 4; ++rr) {
        #pragma unroll
        for (int i = 0; i < 4; ++i) {
            float* p = Cb + (size_t)(rr * 16 + i) * M_;
            #pragma unroll
            for (int cc = 0; cc < 4; ++cc) {
                const float t = fmaf(cm2, acc[rr][cc][i], qsv[rr][i] + ksv[cc]);
                p[cc * 16] = __expf(t);
            }
        }
    }
}

// ---------------------------------------------------------------- launch ----
extern "C" void kernel_launch(void* const* d_in, const int* in_sizes, int n_in,
                              void* d_out, int out_size, void* d_ws, size_t ws_size,
                              hipStream_t stream) {
    const float* Q  = (const float*)d_in[0];
    const float* KV = (const float*)d_in[1];
    const float* ls = (const float*)d_in[2];
    float* out = (float*)d_out;

    char* ws = (char*)d_ws;
    _Float16* Qh  = (_Float16*)ws;
    _Float16* KTh = (_Float16*)(ws + (size_t)8 * 1024 * 1024);
    float*    Qsq = (float*)(ws + (size_t)16 * 1024 * 1024);
    float*    Ksq = (float*)(ws + (size_t)16 * 1024 * 1024 + 128 * 1024);

    prep_q <<<dim3(B_ * N_ / 4), 256, 0, stream>>>(Q, Qh, Qsq);
    prep_kv<<<dim3(M_ / 256, B_), 256, 0, stream>>>(KV, KTh, Ksq);
    gauss_gemm<<<dim3(256, B_), 256, 0, stream>>>(Qh, KTh, Qsq, Ksq, ls, out);
}

// Round 3
// 305.577 us; speedup vs baseline: 1.1726x; 1.0072x over previous
//
#include <hip/hip_runtime.h>

// GaussianKernel: out[b,n,m] = exp(inv2s * (||Q[b,n]||^2 + ||KV[b,:,m]||^2 - 2*Q[b,n]·KV[b,:,m]))
// B=16, N=2048, M=2048, D=128, fp32 in/out.
//
// R4 (on top of R3's K-split + reg-pipeline + 3 blocks/CU):
//  - SWAPPED-OPERAND MFMA: acc = mfma(bf, af, acc) -> fragment regs hold 4
//    consecutive m values -> epilogue is 16 global_store_dwordx4 per thread
//    (was 64 scalar dword stores). Bit-identical math (same dots, same HW
//    accumulation order).
//  - prep fused into ONE kernel: blocks [0,512) do KV (64 cols x full K, one
//    wave per 32-k chunk, LDS-combined Ksq -> full-GPU occupancy; was 128
//    blocks = half the CUs), blocks [512,8704) do Q rows.

#define B_  16
#define N_  2048
#define M_  2048
#define D_  128

typedef _Float16 half8 __attribute__((ext_vector_type(8)));
typedef float    f32x4 __attribute__((ext_vector_type(4)));

// ------------------------------------------------------------ fused prep ----
// blocks [0,512):   KV[b,k,m] -> KTh[b,m,k] fp16 + Ksq[b,m]
//                   block = 64 columns x 128 k; wave w handles k in [w*32,w*32+32)
// blocks [512,8704): Q -> Qh fp16 + Qsq (4 rows per block)
__global__ __launch_bounds__(256) void prep_all(const float* __restrict__ Q,
                                                const float* __restrict__ KV,
                                                _Float16* __restrict__ Qh,
                                                float* __restrict__ Qsq,
                                                _Float16* __restrict__ KTh,
                                                float* __restrict__ Ksq) {
    const int tid = threadIdx.x;
    if (blockIdx.x < 512) {
        __shared__ float part[4][64];
        const int bx  = blockIdx.x;
        const int b   = bx >> 5;            // 32 blocks per batch
        const int m0  = (bx & 31) << 6;     // 64 columns per block
        const int col = tid & 63;
        const int wv  = tid >> 6;           // k-chunk: [wv*32, wv*32+32)
        const int m   = m0 + col;
        const float* src = KV + (size_t)b * D_ * M_ + (size_t)(wv * 32) * M_ + m;
        _Float16*    dst = KTh + ((size_t)b * M_ + m) * D_ + wv * 32;
        float sq = 0.f;
        union { _Float16 h[32]; int4 v[4]; } buf;
        #pragma unroll
        for (int j = 0; j < 32; ++j) {
            const float v = src[(size_t)j * M_];
            sq = fmaf(v, v, sq);
            buf.h[j] = (_Float16)v;
        }
        #pragma unroll
        for (int j = 0; j < 4; ++j)
            reinterpret_cast<int4*>(dst)[j] = buf.v[j];
        part[wv][col] = sq;
        __syncthreads();
        if (wv == 0)
            Ksq[(size_t)b * M_ + m] =
                part[0][col] + part[1][col] + part[2][col] + part[3][col];
    } else {
        const int row  = (blockIdx.x - 512) * 4 + (tid >> 6);
        const int lane = tid & 63;
        const float2 v = reinterpret_cast<const float2*>(Q + (size_t)row * D_)[lane];
        float sq = v.x * v.x + v.y * v.y;
        union { _Float16 h[2]; unsigned int u; } pk;
        pk.h[0] = (_Float16)v.x;
        pk.h[1] = (_Float16)v.y;
        reinterpret_cast<unsigned int*>(Qh + (size_t)row * D_)[lane] = pk.u;
        #pragma unroll
        for (int off = 32; off > 0; off >>= 1) sq += __shfl_down(sq, off, 64);
        if (lane == 0) Qsq[row] = sq;
    }
}

// ------------------------------------------------------------------ GEMM ----
__global__ __launch_bounds__(256, 3) void gauss_gemm(
    const _Float16* __restrict__ Qh, const _Float16* __restrict__ KTh,
    const float* __restrict__ Qsq,  const float* __restrict__ Ksq,
    const float* __restrict__ ls,   float* __restrict__ out) {
    __shared__ __align__(16) _Float16 Ash[128 * 64];   // 16 KB (one K-half of A)
    __shared__ __align__(16) _Float16 Bsh[128 * 64];   // 16 KB (one K-half of B)

    const int b    = blockIdx.y;
    const int bx   = blockIdx.x;
    const int n0   = (bx >> 4) << 7;
    const int m0   = (bx & 15) << 7;
    const int tid  = threadIdx.x;
    const int wave = tid >> 6;
    const int lane = tid & 63;

    const _Float16* Ag = Qh  + ((size_t)b * N_ + n0) * D_;
    const _Float16* Bg = KTh + ((size_t)b * M_ + m0) * D_;

    // Staging: granule = 16B (8 halves); swizzle applied on the GLOBAL address
    // (logical granule gc ^ (r&7)); LDS dst stays linear wave-uniform.
    int goff[4];
    #pragma unroll
    for (int j = 0; j < 4; ++j) {
        const int gi = j * 256 + tid;
        const int r  = gi >> 3;
        const int gc = gi & 7;
        goff[j] = r * D_ + ((gc ^ (r & 7)) << 3);
    }
    const int dbase = wave * 512;

    auto STAGE = [&](int h) {
        #pragma unroll
        for (int j = 0; j < 4; ++j) {
            __builtin_amdgcn_global_load_lds(
                (const __attribute__((address_space(1))) unsigned int*)(Ag + h * 64 + goff[j]),
                (__attribute__((address_space(3))) unsigned int*)(&Ash[j * 2048 + dbase]), 16, 0, 0);
            __builtin_amdgcn_global_load_lds(
                (const __attribute__((address_space(1))) unsigned int*)(Bg + h * 64 + goff[j]),
                (__attribute__((address_space(3))) unsigned int*)(&Bsh[j * 2048 + dbase]), 16, 0, 0);
        }
    };

    const int wr  = (wave >> 1) << 6;
    const int wc  = (wave & 1) << 6;
    const int lm  = lane & 15;
    const int kq  = lane >> 4;
    const int fsw = lm & 7;                // read-side XOR (frag row&7 == lm&7)

    auto READ = [&](half8 af[2][4], half8 bf[2][4]) {
        #pragma unroll
        for (int s = 0; s < 2; ++s) {
            const int pc = ((((s << 2) + kq) ^ fsw) << 3);
            #pragma unroll
            for (int rr = 0; rr < 4; ++rr)
                af[s][rr] = *reinterpret_cast<const half8*>(
                    &Ash[(wr + rr * 16 + lm) * 64 + pc]);
            #pragma unroll
            for (int cc = 0; cc < 4; ++cc)
                bf[s][cc] = *reinterpret_cast<const half8*>(
                    &Bsh[(wc + cc * 16 + lm) * 64 + pc]);
        }
    };

    f32x4 acc[4][4] = {};
    // SWAPPED operands: D[i][j] with i = m-offset (kq*4+reg), j = n-offset (lm).
    // Same dot products, same HW accumulation order -> bit-identical values;
    // but now each lane's 4 regs are 4 CONSECUTIVE m -> f32x4 stores.
    auto MFMA = [&](half8 af[2][4], half8 bf[2][4]) {
        #pragma unroll
        for (int s = 0; s < 2; ++s)
            #pragma unroll
            for (int rr = 0; rr < 4; ++rr)
                #pragma unroll
                for (int cc = 0; cc < 4; ++cc)
                    acc[rr][cc] = __builtin_amdgcn_mfma_f32_16x16x32_f16(
                        bf[s][cc], af[s][rr], acc[rr][cc], 0, 0, 0);
    };

    STAGE(0);
    __syncthreads();                       // h0 in LDS

    half8 a0[2][4], b0[2][4];
    READ(a0, b0);                          // all h0 frags -> regs
    __syncthreads();                       // LDS reusable

    STAGE(1);                              // h1 in flight ...
    MFMA(a0, b0);                          // ... hidden under h0's 32 MFMAs
    __syncthreads();                       // h1 in LDS

    half8 a1[2][4], b1[2][4];
    READ(a1, b1);
    MFMA(a1, b1);

    // ---- epilogue: exp + f32x4 stores (per wave instr: 16 rows x 64B runs) ----
    const float inv2s = -0.5f * __expf(-2.0f * ls[0]);
    const float cm2   = -2.0f * inv2s;
    const float* qsq = Qsq + (size_t)b * N_ + n0;
    const float* ksq = Ksq + (size_t)b * M_ + m0;

    float qv[4];
    #pragma unroll
    for (int rr = 0; rr < 4; ++rr) qv[rr] = inv2s * qsq[wr + rr * 16 + lm];
    f32x4 kv[4];
    #pragma unroll
    for (int cc = 0; cc < 4; ++cc) {
        const f32x4 kr = *reinterpret_cast<const f32x4*>(&ksq[wc + cc * 16 + (kq << 2)]);
        #pragma unroll
        for (int e = 0; e < 4; ++e) kv[cc][e] = inv2s * kr[e];
    }

    float* Cb = out + ((size_t)b * N_ + n0 + wr + lm) * M_ + m0 + wc + (kq << 2);
    #pragma unroll
    for (int rr = 0; rr < 4; ++rr) {
        float* p = Cb + (size_t)(rr * 16) * M_;
        #pragma unroll
        for (int cc = 0; cc < 4; ++cc) {
            f32x4 v;
            #pragma unroll
            for (int e = 0; e < 4; ++e)
                v[e] = __expf(fmaf(cm2, acc[rr][cc][e], qv[rr] + kv[cc][e]));
            *reinterpret_cast<f32x4*>(p + cc * 16) = v;
        }
    }
}

// ---------------------------------------------------------------- launch ----
extern "C" void kernel_launch(void* const* d_in, const int* in_sizes, int n_in,
                              void* d_out, int out_size, void* d_ws, size_t ws_size,
                              hipStream_t stream) {
    const float* Q  = (const float*)d_in[0];
    const float* KV = (const float*)d_in[1];
    const float* ls = (const float*)d_in[2];
    float* out = (float*)d_out;

    char* ws = (char*)d_ws;
    _Float16* Qh  = (_Float16*)ws;
    _Float16* KTh = (_Float16*)(ws + (size_t)8 * 1024 * 1024);
    float*    Qsq = (float*)(ws + (size_t)16 * 1024 * 1024);
    float*    Ksq = (float*)(ws + (size_t)16 * 1024 * 1024 + 128 * 1024);

    prep_all<<<dim3(512 + B_ * N_ / 4), 256, 0, stream>>>(Q, KV, Qh, Qsq, KTh, Ksq);
    gauss_gemm<<<dim3(256, B_), 256, 0, stream>>>(Qh, KTh, Qsq, Ksq, ls, out);
}